// Round 2
// baseline (460.773 us; speedup 1.0000x reference)
//
#include <hip/hip_runtime.h>
#include <math.h>

// Problem constants: x = (16, 32, 65536) fp32. One block per row.
#define LROW   65536
#define NROWS  512              // 16*32
#define NT     1024             // threads per block (16 waves)
#define NW     (NT / 64)        // 16 waves
#define EPT    (LROW / NT)      // 64 elements per thread, register-resident
#define HALO   5

#define TREND_SCALING       0.6f
#define DETAIL_PRESERVATION 0.85f
#define SPIKE_THRESHOLD     3.5f
#define SPIKE_DAMPING       0.35f
#define EPSV                1e-6f

// Element accessor over [ -5, EPT+4 ]: halo regs outside, data inside.
// Only used with compile-time-constant indices inside fully-unrolled loops,
// so the select folds away and everything stays in registers.
#define X(i) ((i) < 0 ? hl[(i) + 5] : ((i) >= EPT ? hr[(i) - EPT] : data[(i)]))

// ---------------------------------------------------------------------------
// k_fused: entire 2-iteration denoise for one row per block.
//   - row data register-resident (64 floats/thread)
//   - per-iteration: LDS halo exchange -> residual stats (f64, deterministic
//     order: 64-lane butterfly + 16 wave partials summed in fixed order by
//     every thread) -> threshold -> in-place apply (shift-by-5 scheme)
//   - row 'reflect' padding handled at tid 0 / NT-1 (block == full row)
// No cross-block dependencies, no workspace, single launch.
// ---------------------------------------------------------------------------
__global__ __launch_bounds__(NT) void k_fused(const float* __restrict__ x,
                                              float* __restrict__ out,
                                              const float* __restrict__ k5,
                                              const float* __restrict__ k11) {
    __shared__ float eL[NT * 5];    // each thread's first 5 elements
    __shared__ float eR[NT * 5];    // each thread's last 5 elements
    __shared__ double wred[2 * NW]; // per-wave (s, q) partials

    const int row = blockIdx.x;
    const int tid = threadIdx.x;
    const size_t base = (size_t)row * LROW + (size_t)tid * EPT;
    const float w5 = k5[0];
    const float w11 = k11[0];

    float data[EPT];
    // Load: 16 x float4 per thread, all in flight together. Lane stride is
    // 256 B; the 16 unrolled loads jointly cover full cachelines, and they
    // are concurrently outstanding so L2 merges sectors.
    {
        const float4* g4 = (const float4*)(x + base);
#pragma unroll
        for (int j = 0; j < EPT / 4; j++) {
            float4 t = g4[j];
            data[4 * j] = t.x;
            data[4 * j + 1] = t.y;
            data[4 * j + 2] = t.z;
            data[4 * j + 3] = t.w;
        }
    }

    float hl[5], hr[5], t5[5];

#pragma unroll 1   // keep the iteration loop runtime: body ~18KB fits I-cache once
    for (int it = 0; it < 2; ++it) {
        // ---- halo exchange (edges of each thread's 64-element span) ----
#pragma unroll
        for (int j = 0; j < 5; j++) {
            eL[tid * 5 + j] = data[j];
            eR[tid * 5 + j] = data[EPT - 5 + j];
        }
        __syncthreads();   // also protects WAR on wred from previous iteration
        if (tid == 0) {
            // positions -5..-1 reflect to x[5..1]
#pragma unroll
            for (int j = 0; j < 5; j++) hl[j] = data[5 - j];
        } else {
#pragma unroll
            for (int j = 0; j < 5; j++) hl[j] = eR[(tid - 1) * 5 + j];
        }
        if (tid == NT - 1) {
            // positions LROW..LROW+4 reflect to x[LROW-2 .. LROW-6] = data[62-j]
#pragma unroll
            for (int j = 0; j < 5; j++) hr[j] = data[62 - j];
        } else {
#pragma unroll
            for (int j = 0; j < 5; j++) hr[j] = eL[(tid + 1) * 5 + j];
        }

        // ---- residual stats: r = cur - box5(cur), f64 accumulation ----
        double s = 0.0, q = 0.0;
#pragma unroll
        for (int k = 0; k < EPT; k++) {
            float lac = 0.f;
#pragma unroll
            for (int d = 0; d < 5; d++) lac = fmaf(X(k - 2 + d), w5, lac);
            float r = data[k] - lac;
            s += (double)r;
            q += (double)r * (double)r;
        }
#pragma unroll
        for (int off = 32; off > 0; off >>= 1) {
            s += __shfl_xor(s, off);
            q += __shfl_xor(q, off);
        }
        {
            const int lane = tid & 63, wid = tid >> 6;
            if (lane == 0) { wred[wid] = s; wred[wid + NW] = q; }
        }
        __syncthreads();   // also protects WAR on eL/eR (all reads done above)

        // every thread redundantly finalizes threshold (fixed order, f64)
        double S = 0.0, Q = 0.0;
#pragma unroll
        for (int w = 0; w < NW; w++) { S += wred[w]; Q += wred[w + NW]; }
        const double N = (double)LROW;
        double var = (Q - S * S / N) / (N - 1.0);
        if (var < 0.0) var = 0.0;
        const float th = fmaxf((float)sqrt(var), EPSV) * SPIKE_THRESHOLD;

        // ---- apply: o[k] from x[k-5..k+5]; write o[k] into data[k-5]
        // (x[k-5] is dead once element k is computed), first 5 into t5.
#pragma unroll
        for (int k = 0; k < EPT; k++) {
            float lac = 0.f, tac = 0.f;
#pragma unroll
            for (int d = 0; d < 5; d++) lac = fmaf(X(k - 2 + d), w5, lac);
#pragma unroll
            for (int d = 0; d < 11; d++) tac = fmaf(X(k - 5 + d), w11, tac);
            float cur = data[k];
            float r = cur - lac;
            r = (fabsf(r) > th) ? r * SPIKE_DAMPING : r;
            float comb = (1.0f - TREND_SCALING) * lac + TREND_SCALING * tac;
            float o = comb + DETAIL_PRESERVATION * r;
            if (k < 5) t5[k] = o; else data[k - 5] = o;
        }
        // shift back so data[k] == o[k]
#pragma unroll
        for (int j = EPT - 1; j >= 5; j--) data[j] = data[j - 5];
#pragma unroll
        for (int j = 0; j < 5; j++) data[j] = t5[j];
    }

    // ---- store final result ----
    {
        float4* o4 = (float4*)(out + base);
#pragma unroll
        for (int j = 0; j < EPT / 4; j++) {
            o4[j] = make_float4(data[4 * j], data[4 * j + 1],
                                data[4 * j + 2], data[4 * j + 3]);
        }
    }
}

extern "C" void kernel_launch(void* const* d_in, const int* in_sizes, int n_in,
                              void* d_out, int out_size, void* d_ws, size_t ws_size,
                              hipStream_t stream) {
    (void)in_sizes; (void)n_in; (void)out_size; (void)d_ws; (void)ws_size;
    const float* x = (const float*)d_in[0];
    const float* k5 = (const float*)d_in[1];
    const float* k11 = (const float*)d_in[2];
    float* out = (float*)d_out;

    hipLaunchKernelGGL(k_fused, dim3(NROWS), dim3(NT), 0, stream, x, out, k5, k11);
}